// Round 9
// baseline (258.994 us; speedup 1.0000x reference)
//
#include <hip/hip_runtime.h>

// Problem: B=2, S=2048, D=1024, H=16, DK=64. fp32 in/out, bf16 MFMA inside.
constexpr float kScale = 0.125f;            // 1/sqrt(64)
constexpr float kLog2e = 1.44269504088896f; // softmax runs in exp2 domain

typedef __attribute__((ext_vector_type(8))) short bf16x8;
typedef __attribute__((ext_vector_type(4))) float f32x4;

static __device__ __forceinline__ ushort f2bf(float f) {
  uint u = __float_as_uint(f);
  return (ushort)((u + 0x7fffu + ((u >> 16) & 1u)) >> 16);  // RNE
}

static __device__ __forceinline__ float exp2_hw(float x) {
#if __has_builtin(__builtin_amdgcn_exp2f)
  return __builtin_amdgcn_exp2f(x);   // bare v_exp_f32, compiler-scheduled
#else
  return exp2f(x);
#endif
}

#define GLD_LDS16(g, l)                                        \
  __builtin_amdgcn_global_load_lds(                            \
      (const __attribute__((address_space(1))) void*)(g),      \
      (__attribute__((address_space(3))) void*)(l), 16, 0, 0)

// ---------------------------------------------------------------------------
// fp32 -> bf16 pack of x | qkv_w | out_w into one contiguous dest, 8 elems/thr
// ---------------------------------------------------------------------------
__global__ __launch_bounds__(256) void cvt3_f32_bf16(
    const float* __restrict__ s0, const float* __restrict__ s1,
    const float* __restrict__ s2, ushort* __restrict__ dst) {
  const int i = blockIdx.x * 256 + threadIdx.x;  // 8-elem chunks, 1048576 total
  const float* src;
  int off;
  if (i < 524288) { src = s0; off = i; }
  else if (i < 917504) { src = s1; off = i - 524288; }
  else { src = s2; off = i - 917504; }
  const float4 a = ((const float4*)src)[2 * off];
  const float4 b = ((const float4*)src)[2 * off + 1];
  union { ushort u[8]; int4 v; } r;
  r.u[0] = f2bf(a.x); r.u[1] = f2bf(a.y); r.u[2] = f2bf(a.z); r.u[3] = f2bf(a.w);
  r.u[4] = f2bf(b.x); r.u[5] = f2bf(b.y); r.u[6] = f2bf(b.z); r.u[7] = f2bf(b.w);
  ((int4*)dst)[i] = r.v;
}

// ---------------------------------------------------------------------------
// Per-64x64-tile mask classification: 1=all-nonzero, 2=all-zero, 0=mixed
// ---------------------------------------------------------------------------
__global__ __launch_bounds__(256) void mask_flags(
    const int* __restrict__ mask, int* __restrict__ flags) {
  const int bid = blockIdx.x;            // b*1024 + qt*32 + kt
  const int b = bid >> 10, qt = (bid >> 5) & 31, kt = bid & 31;
  const int t = threadIdx.x;
  bool nz = true, z = true;
#pragma unroll
  for (int i = 0; i < 4; ++i) {
    const int f = t + i * 256;           // 0..1023
    const int row = f >> 4, c4 = (f & 15) * 4;
    const int4 v = *(const int4*)&mask[(size_t)(b * 2048 + qt * 64 + row) * 2048 + kt * 64 + c4];
    nz = nz && v.x && v.y && v.z && v.w;
    z = z && !v.x && !v.y && !v.z && !v.w;
  }
  __shared__ int snz[4], sz[4];
  const int wnz = __all(nz), wz = __all(z);
  if ((t & 63) == 0) { snz[t >> 6] = wnz; sz[t >> 6] = wz; }
  __syncthreads();
  if (t == 0) {
    const int a = snz[0] & snz[1] & snz[2] & snz[3];
    const int c = sz[0] & sz[1] & sz[2] & sz[3];
    flags[bid] = a ? 1 : (c ? 2 : 0);
  }
}

// ---------------------------------------------------------------------------
// bf16 GEMM (m97 structure): C = A @ W^T (+bias). 128x128 tile, 4 waves, BK=32,
// global_load_lds staging, swizzled LDS, 16x16x32 MFMA.
// MODE 1: bias + scatter: Q (pre-scaled by kScale*log2e) / K -> [bh][s][dk];
//         V -> [bh][dk][s] (transposed here).  MODE 0: bias + fp32 out.
// ---------------------------------------------------------------------------
template <int MODE>
__global__ __launch_bounds__(256) void gemm_bt(
    const ushort* __restrict__ A, const ushort* __restrict__ W,
    const float* __restrict__ bias, ushort* __restrict__ q_ws,
    ushort* __restrict__ k_ws, ushort* __restrict__ v_ws,
    float* __restrict__ outf) {
  __shared__ __align__(16) ushort As[128 * 32];
  __shared__ __align__(16) ushort Bs[128 * 32];
  const int tid = threadIdx.x;
  const int m0 = blockIdx.x * 128, n0 = blockIdx.y * 128;
  const int w = tid >> 6, lane = tid & 63;
  const int wr = w >> 1, wc = w & 1;
  const int lrow = lane & 15, kg = lane >> 4;

  f32x4 acc[4][4] = {};

  for (int k0 = 0; k0 < 1024; k0 += 32) {
    __syncthreads();
#pragma unroll
    for (int i = 0; i < 4; ++i) {
      const int f = tid + i * 256;
      const int fl = f & 511;
      const int row = fl >> 2, kgd = fl & 3;
      const int kgs = kgd ^ ((row >> 1) & 3);
      const ushort* gsrc = (f < 512)
          ? &A[(size_t)(m0 + row) * 1024 + k0 + kgs * 8]
          : &W[(size_t)(n0 + row) * 1024 + k0 + kgs * 8];
      ushort* ldst = (f < 512) ? &As[fl * 8] : &Bs[fl * 8];
      GLD_LDS16(gsrc, ldst);
    }
    __syncthreads();

    bf16x8 av[4], bv[4];
#pragma unroll
    for (int m = 0; m < 4; ++m) {
      const int row = wr * 64 + m * 16 + lrow;
      av[m] = *(const bf16x8*)&As[row * 32 + (kg ^ ((row >> 1) & 3)) * 8];
    }
#pragma unroll
    for (int n = 0; n < 4; ++n) {
      const int row = wc * 64 + n * 16 + lrow;
      bv[n] = *(const bf16x8*)&Bs[row * 32 + (kg ^ ((row >> 1) & 3)) * 8];
    }
    __builtin_amdgcn_s_setprio(1);
#pragma unroll
    for (int m = 0; m < 4; ++m)
#pragma unroll
      for (int n = 0; n < 4; ++n)
        acc[m][n] = __builtin_amdgcn_mfma_f32_16x16x32_bf16(av[m], bv[n], acc[m][n], 0, 0, 0);
    __builtin_amdgcn_s_setprio(0);
  }

  // C/D: col = lane&15, row = (lane>>4)*4 + j
  if (MODE == 1) {
#pragma unroll
    for (int n = 0; n < 4; ++n) {
      const int col = n0 + wc * 64 + n * 16 + lrow;
      const float bj = bias[col];
      const int sel = col >> 10, h = (col >> 6) & 15, dk = col & 63;
      if (sel == 2) {
        // V: [bh][dk][s], j walks s contiguously -> uint2 stores
#pragma unroll
        for (int m = 0; m < 4; ++m) {
          const int mrow0 = m0 + wr * 64 + m * 16 + kg * 4;
          const int b = mrow0 >> 11, s = mrow0 & 2047;
          union { ushort u[4]; uint2 v; } pk;
#pragma unroll
          for (int j = 0; j < 4; ++j) pk.u[j] = f2bf(acc[m][n][j] + bj);
          *(uint2*)&v_ws[((size_t)(b * 16 + h) * 64 + dk) * 2048 + s] = pk.v;
        }
      } else {
        // Q pre-scaled by kScale*log2e so flash softmax runs in exp2 domain
        const float scl = (sel == 0) ? kScale * kLog2e : 1.f;
        ushort* dst = sel == 0 ? q_ws : k_ws;
#pragma unroll
        for (int m = 0; m < 4; ++m)
#pragma unroll
          for (int j = 0; j < 4; ++j) {
            const int mrow = m0 + wr * 64 + m * 16 + kg * 4 + j;
            const int b = mrow >> 11, s = mrow & 2047;
            dst[((size_t)(b * 16 + h) * 2048 + s) * 64 + dk] =
                f2bf((acc[m][n][j] + bj) * scl);
          }
      }
    }
  } else {
#pragma unroll
    for (int n = 0; n < 4; ++n) {
      const int col = n0 + wc * 64 + n * 16 + lrow;
      const float bj = bias[col];
#pragma unroll
      for (int m = 0; m < 4; ++m)
#pragma unroll
        for (int j = 0; j < 4; ++j) {
          const int mrow = m0 + wr * 64 + m * 16 + kg * 4 + j;
          outf[(size_t)mrow * 1024 + col] = acc[m][n][j] + bj;
        }
    }
  }
}

// ---------------------------------------------------------------------------
// Flash attention v5: r6 structure (swapped QK^T, per-lane softmax, K/V LDS
// double-buffer via global_load_lds, defer-max) + exp2-domain softmax
// (builtin, not asm), in-place softmax on sacc, tree reductions.
// ---------------------------------------------------------------------------
__global__ __launch_bounds__(256) void flash_attn(
    const ushort* __restrict__ Q, const ushort* __restrict__ K,
    const ushort* __restrict__ Vt, const int* __restrict__ mask,
    const int* __restrict__ flags, ushort* __restrict__ AO) {
  __shared__ __align__(16) ushort Ks[2][64 * 64];  // [k-row][dk], swizzled
  __shared__ __align__(16) ushort Vs[2][64 * 64];  // [dk-row][k], swizzled
  __shared__ __align__(16) ushort Ps[4][16 * 64];  // per-wave P, swizzled

  const int id = blockIdx.x;
  const int xcd = id & 7, sub = id >> 3;
  const int bh = xcd * 4 + (sub >> 5), qt = sub & 31;
  const int b = bh >> 4, h = bh & 15;
  const int q0 = qt * 64;
  const int tid = threadIdx.x, w = tid >> 6, lane = tid & 63;
  const int lrow = lane & 15, kg = lane >> 4;
  const int t7 = lrow & 7;
  const size_t kbase = (size_t)bh * 2048 * 64;  // Q,K: [bh][2048][64]
  const size_t vbase = (size_t)bh * 64 * 2048;  // Vt:  [bh][64][2048]
  const int qrow = q0 + w * 16 + lrow;          // this lane's q-row

  // staging: LDS byte addr = wave-base + lane*16 (linear), as required
  const int srow = tid >> 3, sg = tid & 7;

  bf16x8 bq[2];
#pragma unroll
  for (int s = 0; s < 2; ++s)
    bq[s] = *(const bf16x8*)&Q[kbase + (size_t)qrow * 64 + s * 32 + kg * 8];

  float mi = -1e30f, li = 0.f;
  f32x4 oacc[4] = {};  // [n][j]: O[q=kg*4+j][dk=n*16+lrow]
  ushort* pl = &Ps[w][0];
  const int* fbase = flags + (b * 32 + qt) * 32;

  auto STAGE = [&](int buf, int kt) {
    const int k0 = kt * 64;
#pragma unroll
    for (int i = 0; i < 2; ++i) {
      const int r = srow + i * 32;
      GLD_LDS16(&K[kbase + (size_t)(k0 + r) * 64 + (sg ^ (r & 7)) * 8],
                &Ks[buf][r * 64 + sg * 8]);
      GLD_LDS16(&Vt[vbase + (size_t)r * 2048 + k0 + (sg ^ (r & 7)) * 8],
                &Vs[buf][r * 64 + sg * 8]);
    }
  };

  STAGE(0, 0);
  __syncthreads();  // drains vmcnt(0): tile 0 ready

  for (int kt = 0; kt < 32; ++kt) {
    const int cur = kt & 1;
    if (kt < 31) STAGE(cur ^ 1, kt + 1);  // async, lands before next barrier
    const int flag = fbase[kt];
    const int k0 = kt * 64;

    // S^T = K @ Q^T : sacc[m][j] = S[k0+m*16+kg*4+j][q=qrow] (x log2e)
    f32x4 sacc[4] = {};
    __builtin_amdgcn_s_setprio(1);
#pragma unroll
    for (int s = 0; s < 2; ++s)
#pragma unroll
      for (int m = 0; m < 4; ++m) {
        const bf16x8 ak = *(const bf16x8*)
            &Ks[cur][(m * 16 + lrow) * 64 + ((s * 4 + kg) ^ t7) * 8];
        sacc[m] = __builtin_amdgcn_mfma_f32_16x16x32_bf16(ak, bq[s], sacc[m], 0, 0, 0);
      }
    __builtin_amdgcn_s_setprio(0);

    // mask in place
    if (flag == 2) {
#pragma unroll
      for (int m = 0; m < 4; ++m)
#pragma unroll
        for (int j = 0; j < 4; ++j) sacc[m][j] = -1e9f;
    } else if (flag == 0) {
      const int* mrow = &mask[(size_t)(b * 2048 + qrow) * 2048 + k0];
#pragma unroll
      for (int m = 0; m < 4; ++m)
#pragma unroll
        for (int j = 0; j < 4; ++j)
          if (mrow[m * 16 + kg * 4 + j] == 0) sacc[m][j] = -1e9f;
    }

    // per-lane row max: tree (v_max3-fusable), then 2-step cross-kg reduce
    float tm[4];
#pragma unroll
    for (int m = 0; m < 4; ++m)
      tm[m] = fmaxf(fmaxf(sacc[m][0], sacc[m][1]), fmaxf(sacc[m][2], sacc[m][3]));
    float rmax = fmaxf(fmaxf(tm[0], tm[1]), fmaxf(tm[2], tm[3]));
    rmax = fmaxf(rmax, __shfl_xor(rmax, 16));
    rmax = fmaxf(rmax, __shfl_xor(rmax, 32));

    // defer-max (T13, exp2 domain): rescale only if max grew past threshold
    if (!__all(rmax <= mi + 8.f)) {
      const float newm = fmaxf(mi, rmax);
      const float corr = exp2_hw(mi - newm);
      mi = newm;
      li *= corr;
      float cf[4];
#pragma unroll
      for (int j = 0; j < 4; ++j) cf[j] = __shfl(corr, kg * 4 + j);
#pragma unroll
      for (int n = 0; n < 4; ++n)
#pragma unroll
        for (int j = 0; j < 4; ++j) oacc[n][j] *= cf[j];
    }

    // exp2 in place + tree sum
    float rs[4];
#pragma unroll
    for (int m = 0; m < 4; ++m) {
#pragma unroll
      for (int j = 0; j < 4; ++j) sacc[m][j] = exp2_hw(sacc[m][j] - mi);
      rs[m] = (sacc[m][0] + sacc[m][1]) + (sacc[m][2] + sacc[m][3]);
    }
    float rsum = (rs[0] + rs[1]) + (rs[2] + rs[3]);
    rsum += __shfl_xor(rsum, 16);
    rsum += __shfl_xor(rsum, 32);
    li += rsum;

    // P -> per-wave LDS (bf16), 16B-granule XOR swizzle; 4x b64 writes
#pragma unroll
    for (int m = 0; m < 4; ++m) {
      union { ushort u[4]; uint2 v; } pk;
#pragma unroll
      for (int j = 0; j < 4; ++j) pk.u[j] = f2bf(sacc[m][j]);
      *(uint2*)&pl[lrow * 64 + ((m * 2 + (kg >> 1)) ^ t7) * 8 + (kg & 1) * 4] = pk.v;
    }
    asm volatile("s_waitcnt lgkmcnt(0)" ::: "memory");
    __builtin_amdgcn_sched_barrier(0);

    // O += P @ V
    __builtin_amdgcn_s_setprio(1);
#pragma unroll
    for (int s2 = 0; s2 < 2; ++s2) {
      const bf16x8 pa = *(const bf16x8*)&pl[lrow * 64 + ((s2 * 4 + kg) ^ t7) * 8];
#pragma unroll
      for (int n = 0; n < 4; ++n) {
        const int r = n * 16 + lrow;
        const bf16x8 bv = *(const bf16x8*)
            &Vs[cur][r * 64 + ((s2 * 4 + kg) ^ t7) * 8];
        oacc[n] = __builtin_amdgcn_mfma_f32_16x16x32_bf16(pa, bv, oacc[n], 0, 0, 0);
      }
    }
    __builtin_amdgcn_s_setprio(0);

    __syncthreads();  // drain staged kt+1 (vmcnt) + all waves done with cur
  }

  // epilogue: normalize (li redistributed via shfl), bf16 store
#pragma unroll
  for (int j = 0; j < 4; ++j) {
    const float lj = __shfl(li, kg * 4 + j);
    const float inv = 1.f / lj;
    const int q = q0 + w * 16 + kg * 4 + j;
#pragma unroll
    for (int n = 0; n < 4; ++n)
      AO[(size_t)(b * 2048 + q) * 1024 + h * 64 + n * 16 + lrow] =
          f2bf(oacc[n][j] * inv);
  }
}

// ---------------------------------------------------------------------------
extern "C" void kernel_launch(void* const* d_in, const int* in_sizes, int n_in,
                              void* d_out, int out_size, void* d_ws,
                              size_t ws_size, hipStream_t stream) {
  const float* x = (const float*)d_in[0];
  const int* mask = (const int*)d_in[1];
  const float* qkv_w = (const float*)d_in[2];
  const float* qkv_b = (const float*)d_in[3];
  const float* out_w = (const float*)d_in[4];
  const float* out_b = (const float*)d_in[5];
  float* out = (float*)d_out;

  ushort* p = (ushort*)d_ws;
  ushort* xb = p;      p += 4194304;   // x bf16 [4096][1024]      (contiguous
  ushort* qkvwb = p;   p += 3145728;   // qkv_w bf16 [3072][1024]   cvt3 dest)
  ushort* outwb = p;   p += 1048576;   // out_w bf16 [1024][1024]
  ushort* q_ws = p;    p += 4194304;   // [32][2048][64] (pre-scaled, exp2 dom.)
  ushort* k_ws = p;    p += 4194304;   // [32][2048][64]
  ushort* vt_ws = p;   p += 4194304;   // [32][64][2048] (transposed in GEMM)
  ushort* ao_ws = p;   p += 4194304;   // [4096][1024] bf16
  int* flags = (int*)p;                // [2][32][32]

  cvt3_f32_bf16<<<4096, 256, 0, stream>>>(x, qkv_w, out_w, xb);
  mask_flags<<<2048, 256, 0, stream>>>(mask, flags);
  gemm_bt<1><<<dim3(32, 24), 256, 0, stream>>>(xb, qkvwb, qkv_b, q_ws, k_ws,
                                               vt_ws, nullptr);
  flash_attn<<<1024, 256, 0, stream>>>(q_ws, k_ws, vt_ws, mask, flags, ao_ws);
  gemm_bt<0><<<dim3(32, 8), 256, 0, stream>>>(ao_ws, outwb, out_b, nullptr,
                                              nullptr, nullptr, out);
}

// Round 10
// 228.305 us; speedup vs baseline: 1.1344x; 1.1344x over previous
//
#include <hip/hip_runtime.h>

// Problem: B=2, S=2048, D=1024, H=16, DK=64. fp32 in/out, bf16 MFMA inside.
constexpr float kScale = 0.125f;  // 1/sqrt(64)

typedef __attribute__((ext_vector_type(8))) short bf16x8;
typedef __attribute__((ext_vector_type(4))) float f32x4;

static __device__ __forceinline__ ushort f2bf(float f) {
  uint u = __float_as_uint(f);
  return (ushort)((u + 0x7fffu + ((u >> 16) & 1u)) >> 16);  // RNE
}

#define GLD_LDS16(g, l)                                        \
  __builtin_amdgcn_global_load_lds(                            \
      (const __attribute__((address_space(1))) void*)(g),      \
      (__attribute__((address_space(3))) void*)(l), 16, 0, 0)

// ---------------------------------------------------------------------------
// fp32 -> bf16 pack of x | qkv_w | out_w into one contiguous dest, 8 elems/thr
// ---------------------------------------------------------------------------
__global__ __launch_bounds__(256) void cvt3_f32_bf16(
    const float* __restrict__ s0, const float* __restrict__ s1,
    const float* __restrict__ s2, ushort* __restrict__ dst) {
  const int i = blockIdx.x * 256 + threadIdx.x;  // 8-elem chunks, 1048576 total
  const float* src;
  int off;
  if (i < 524288) { src = s0; off = i; }
  else if (i < 917504) { src = s1; off = i - 524288; }
  else { src = s2; off = i - 917504; }
  const float4 a = ((const float4*)src)[2 * off];
  const float4 b = ((const float4*)src)[2 * off + 1];
  union { ushort u[8]; int4 v; } r;
  r.u[0] = f2bf(a.x); r.u[1] = f2bf(a.y); r.u[2] = f2bf(a.z); r.u[3] = f2bf(a.w);
  r.u[4] = f2bf(b.x); r.u[5] = f2bf(b.y); r.u[6] = f2bf(b.z); r.u[7] = f2bf(b.w);
  ((int4*)dst)[i] = r.v;
}

// ---------------------------------------------------------------------------
// Per-64x64-tile mask classification: 1=all-nonzero, 2=all-zero, 0=mixed
// ---------------------------------------------------------------------------
__global__ __launch_bounds__(256) void mask_flags(
    const int* __restrict__ mask, int* __restrict__ flags) {
  const int bid = blockIdx.x;            // b*1024 + qt*32 + kt
  const int b = bid >> 10, qt = (bid >> 5) & 31, kt = bid & 31;
  const int t = threadIdx.x;
  bool nz = true, z = true;
#pragma unroll
  for (int i = 0; i < 4; ++i) {
    const int f = t + i * 256;           // 0..1023
    const int row = f >> 4, c4 = (f & 15) * 4;
    const int4 v = *(const int4*)&mask[(size_t)(b * 2048 + qt * 64 + row) * 2048 + kt * 64 + c4];
    nz = nz && v.x && v.y && v.z && v.w;
    z = z && !v.x && !v.y && !v.z && !v.w;
  }
  __shared__ int snz[4], sz[4];
  const int wnz = __all(nz), wz = __all(z);
  if ((t & 63) == 0) { snz[t >> 6] = wnz; sz[t >> 6] = wz; }
  __syncthreads();
  if (t == 0) {
    const int a = snz[0] & snz[1] & snz[2] & snz[3];
    const int c = sz[0] & sz[1] & sz[2] & sz[3];
    flags[bid] = a ? 1 : (c ? 2 : 0);
  }
}

// ---------------------------------------------------------------------------
// bf16 GEMM: C = A @ W^T (+bias). 128x128 tile, 4 waves, BK=64 (halved barrier
// count vs m97's BK=32; 32 MFMA/phase), global_load_lds staging, 3-bit XOR
// granule swizzle, 16x16x32 MFMA.
// MODE 1: bias + scatter: Q (pre-scaled kScale) / K -> [bh][s][dk];
//         V -> [bh][dk][s] (transposed here).  MODE 0: bias + fp32 out.
// ---------------------------------------------------------------------------
template <int MODE>
__global__ __launch_bounds__(256) void gemm_bt(
    const ushort* __restrict__ A, const ushort* __restrict__ W,
    const float* __restrict__ bias, ushort* __restrict__ q_ws,
    ushort* __restrict__ k_ws, ushort* __restrict__ v_ws,
    float* __restrict__ outf) {
  __shared__ __align__(16) ushort As[128 * 64];  // [row][64k], swizzled granules
  __shared__ __align__(16) ushort Bs[128 * 64];
  const int tid = threadIdx.x;
  const int m0 = blockIdx.x * 128, n0 = blockIdx.y * 128;
  const int w = tid >> 6, lane = tid & 63;
  const int wr = w >> 1, wc = w & 1;
  const int lrow = lane & 15, kg = lane >> 4;

  f32x4 acc[4][4] = {};

  for (int k0 = 0; k0 < 1024; k0 += 64) {
    __syncthreads();
    // stage 128x64 A + 128x64 W: 2048 16B-granules, 8 per thread.
    // dest linear per wave: byte off = (tid + i*256)*16 = wavebase + lane*16 ok
#pragma unroll
    for (int i = 0; i < 8; ++i) {
      const int f = tid + i * 256;       // 0..2047
      const int fl = f & 1023;
      const int row = fl >> 3, kgd = fl & 7;
      const int kgs = kgd ^ (row & 7);   // inverse-swizzled global granule
      const ushort* gsrc = (f < 1024)
          ? &A[(size_t)(m0 + row) * 1024 + k0 + kgs * 8]
          : &W[(size_t)(n0 + row) * 1024 + k0 + kgs * 8];
      ushort* ldst = (f < 1024) ? &As[fl * 8] : &Bs[fl * 8];
      GLD_LDS16(gsrc, ldst);
    }
    __syncthreads();

    bf16x8 av[2][4], bv[2][4];
#pragma unroll
    for (int ks = 0; ks < 2; ++ks) {
#pragma unroll
      for (int m = 0; m < 4; ++m) {
        const int row = wr * 64 + m * 16 + lrow;
        av[ks][m] = *(const bf16x8*)&As[row * 64 + (((ks * 4 + kg)) ^ (row & 7)) * 8];
      }
#pragma unroll
      for (int n = 0; n < 4; ++n) {
        const int row = wc * 64 + n * 16 + lrow;
        bv[ks][n] = *(const bf16x8*)&Bs[row * 64 + (((ks * 4 + kg)) ^ (row & 7)) * 8];
      }
    }
    __builtin_amdgcn_s_setprio(1);
#pragma unroll
    for (int ks = 0; ks < 2; ++ks)
#pragma unroll
      for (int m = 0; m < 4; ++m)
#pragma unroll
        for (int n = 0; n < 4; ++n)
          acc[m][n] = __builtin_amdgcn_mfma_f32_16x16x32_bf16(av[ks][m], bv[ks][n],
                                                              acc[m][n], 0, 0, 0);
    __builtin_amdgcn_s_setprio(0);
  }

  // C/D: col = lane&15, row = (lane>>4)*4 + j
  if (MODE == 1) {
#pragma unroll
    for (int n = 0; n < 4; ++n) {
      const int col = n0 + wc * 64 + n * 16 + lrow;
      const float bj = bias[col];
      const int sel = col >> 10, h = (col >> 6) & 15, dk = col & 63;
      if (sel == 2) {
        // V: [bh][dk][s], j walks s contiguously -> uint2 stores
#pragma unroll
        for (int m = 0; m < 4; ++m) {
          const int mrow0 = m0 + wr * 64 + m * 16 + kg * 4;
          const int b = mrow0 >> 11, s = mrow0 & 2047;
          union { ushort u[4]; uint2 v; } pk;
#pragma unroll
          for (int j = 0; j < 4; ++j) pk.u[j] = f2bf(acc[m][n][j] + bj);
          *(uint2*)&v_ws[((size_t)(b * 16 + h) * 64 + dk) * 2048 + s] = pk.v;
        }
      } else {
        const float scl = (sel == 0) ? kScale : 1.f;  // fold 1/sqrt(dk) into Q
        ushort* dst = sel == 0 ? q_ws : k_ws;
#pragma unroll
        for (int m = 0; m < 4; ++m)
#pragma unroll
          for (int j = 0; j < 4; ++j) {
            const int mrow = m0 + wr * 64 + m * 16 + kg * 4 + j;
            const int b = mrow >> 11, s = mrow & 2047;
            dst[((size_t)(b * 16 + h) * 2048 + s) * 64 + dk] =
                f2bf((acc[m][n][j] + bj) * scl);
          }
      }
    }
  } else {
#pragma unroll
    for (int n = 0; n < 4; ++n) {
      const int col = n0 + wc * 64 + n * 16 + lrow;
      const float bj = bias[col];
#pragma unroll
      for (int m = 0; m < 4; ++m)
#pragma unroll
        for (int j = 0; j < 4; ++j) {
          const int mrow = m0 + wr * 64 + m * 16 + kg * 4 + j;
          outf[(size_t)mrow * 1024 + col] = acc[m][n][j] + bj;
        }
    }
  }
}

// ---------------------------------------------------------------------------
// Flash attention — byte-exact r6 body (measured 88.9us, VGPR 64): swapped
// QK^T (per-lane softmax), K/V LDS double-buffer via global_load_lds
// (pre-swizzled source), 2-phase pipeline, defer-max. kScale pre-folded in Q.
// ---------------------------------------------------------------------------
__global__ __launch_bounds__(256) void flash_attn(
    const ushort* __restrict__ Q, const ushort* __restrict__ K,
    const ushort* __restrict__ Vt, const int* __restrict__ mask,
    const int* __restrict__ flags, ushort* __restrict__ AO) {
  __shared__ __align__(16) ushort Ks[2][64 * 64];  // [k-row][dk], swizzled
  __shared__ __align__(16) ushort Vs[2][64 * 64];  // [dk-row][k], swizzled
  __shared__ __align__(16) ushort Ps[4][16 * 64];  // per-wave P, swizzled

  const int id = blockIdx.x;
  const int xcd = id & 7, sub = id >> 3;
  const int bh = xcd * 4 + (sub >> 5), qt = sub & 31;
  const int b = bh >> 4, h = bh & 15;
  const int q0 = qt * 64;
  const int tid = threadIdx.x, w = tid >> 6, lane = tid & 63;
  const int lrow = lane & 15, kg = lane >> 4;
  const int t7 = lrow & 7;
  const size_t kbase = (size_t)bh * 2048 * 64;  // Q,K: [bh][2048][64]
  const size_t vbase = (size_t)bh * 64 * 2048;  // Vt:  [bh][64][2048]
  const int qrow = q0 + w * 16 + lrow;          // this lane's q-row

  // staging: LDS byte addr = wave-base + lane*16 (linear), as required
  const int srow = tid >> 3, sg = tid & 7;

  bf16x8 bq[2];
#pragma unroll
  for (int s = 0; s < 2; ++s)
    bq[s] = *(const bf16x8*)&Q[kbase + (size_t)qrow * 64 + s * 32 + kg * 8];

  float mi = -1e30f, li = 0.f;
  f32x4 oacc[4] = {};  // [n][j]: O[q=kg*4+j][dk=n*16+lrow]
  ushort* pl = &Ps[w][0];
  const int* fbase = flags + (b * 32 + qt) * 32;

  auto STAGE = [&](int buf, int kt) {
    const int k0 = kt * 64;
#pragma unroll
    for (int i = 0; i < 2; ++i) {
      const int r = srow + i * 32;
      GLD_LDS16(&K[kbase + (size_t)(k0 + r) * 64 + (sg ^ (r & 7)) * 8],
                &Ks[buf][r * 64 + sg * 8]);
      GLD_LDS16(&Vt[vbase + (size_t)r * 2048 + k0 + (sg ^ (r & 7)) * 8],
                &Vs[buf][r * 64 + sg * 8]);
    }
  };

  STAGE(0, 0);
  __syncthreads();  // drains vmcnt(0): tile 0 ready

  for (int kt = 0; kt < 32; ++kt) {
    const int cur = kt & 1;
    if (kt < 31) STAGE(cur ^ 1, kt + 1);  // async, lands before next barrier
    const int flag = fbase[kt];
    const int k0 = kt * 64;

    // S^T = K @ Q^T : sacc[m][j] = S[k0 + m*16 + kg*4 + j][q = qrow]
    f32x4 sacc[4] = {};
    __builtin_amdgcn_s_setprio(1);
#pragma unroll
    for (int s = 0; s < 2; ++s)
#pragma unroll
      for (int m = 0; m < 4; ++m) {
        const bf16x8 ak = *(const bf16x8*)
            &Ks[cur][(m * 16 + lrow) * 64 + ((s * 4 + kg) ^ t7) * 8];
        sacc[m] = __builtin_amdgcn_mfma_f32_16x16x32_bf16(ak, bq[s], sacc[m], 0, 0, 0);
      }
    __builtin_amdgcn_s_setprio(0);

    float sv[16];
#pragma unroll
    for (int m = 0; m < 4; ++m)
#pragma unroll
      for (int j = 0; j < 4; ++j) sv[m * 4 + j] = sacc[m][j];

    if (flag == 2) {
#pragma unroll
      for (int i = 0; i < 16; ++i) sv[i] = -1e9f;
    } else if (flag == 0) {
      const int* mrow = &mask[(size_t)(b * 2048 + qrow) * 2048 + k0];
#pragma unroll
      for (int m = 0; m < 4; ++m)
#pragma unroll
        for (int j = 0; j < 4; ++j)
          if (mrow[m * 16 + kg * 4 + j] == 0) sv[m * 4 + j] = -1e9f;
    }

    // per-lane row max (one q-row/lane) + 2-step cross-kg reduce
    float rmax = sv[0];
#pragma unroll
    for (int i = 1; i < 16; ++i) rmax = fmaxf(rmax, sv[i]);
    rmax = fmaxf(rmax, __shfl_xor(rmax, 16));
    rmax = fmaxf(rmax, __shfl_xor(rmax, 32));

    // defer-max (T13): rescale only if max grew past threshold
    if (!__all(rmax <= mi + 8.f)) {
      const float newm = fmaxf(mi, rmax);
      const float corr = __expf(mi - newm);
      mi = newm;
      li *= corr;
      float cf[4];
#pragma unroll
      for (int j = 0; j < 4; ++j) cf[j] = __shfl(corr, kg * 4 + j);
#pragma unroll
      for (int n = 0; n < 4; ++n)
#pragma unroll
        for (int j = 0; j < 4; ++j) oacc[n][j] *= cf[j];
    }

    float rsum = 0.f;
#pragma unroll
    for (int i = 0; i < 16; ++i) {
      sv[i] = __expf(sv[i] - mi);
      rsum += sv[i];
    }
    rsum += __shfl_xor(rsum, 16);
    rsum += __shfl_xor(rsum, 32);
    li += rsum;

    // P -> per-wave LDS (bf16), 16B-granule XOR swizzle; 4x b64 writes
#pragma unroll
    for (int m = 0; m < 4; ++m) {
      union { ushort u[4]; uint2 v; } pk;
#pragma unroll
      for (int j = 0; j < 4; ++j) pk.u[j] = f2bf(sv[m * 4 + j]);
      *(uint2*)&pl[lrow * 64 + ((m * 2 + (kg >> 1)) ^ t7) * 8 + (kg & 1) * 4] = pk.v;
    }
    asm volatile("s_waitcnt lgkmcnt(0)" ::: "memory");
    __builtin_amdgcn_sched_barrier(0);

    // O += P @ V
    __builtin_amdgcn_s_setprio(1);
#pragma unroll
    for (int s2 = 0; s2 < 2; ++s2) {
      const bf16x8 pa = *(const bf16x8*)&pl[lrow * 64 + ((s2 * 4 + kg) ^ t7) * 8];
#pragma unroll
      for (int n = 0; n < 4; ++n) {
        const int r = n * 16 + lrow;
        const bf16x8 bv = *(const bf16x8*)
            &Vs[cur][r * 64 + ((s2 * 4 + kg) ^ t7) * 8];
        oacc[n] = __builtin_amdgcn_mfma_f32_16x16x32_bf16(pa, bv, oacc[n], 0, 0, 0);
      }
    }
    __builtin_amdgcn_s_setprio(0);

    __syncthreads();  // drain staged kt+1 (vmcnt) + all waves done with cur
  }

  // epilogue: normalize (li redistributed via shfl), bf16 store
#pragma unroll
  for (int j = 0; j < 4; ++j) {
    const float lj = __shfl(li, kg * 4 + j);
    const float inv = 1.f / lj;
    const int q = q0 + w * 16 + kg * 4 + j;
#pragma unroll
    for (int n = 0; n < 4; ++n)
      AO[(size_t)(b * 2048 + q) * 1024 + h * 64 + n * 16 + lrow] =
          f2bf(oacc[n][j] * inv);
  }
}

// ---------------------------------------------------------------------------
extern "C" void kernel_launch(void* const* d_in, const int* in_sizes, int n_in,
                              void* d_out, int out_size, void* d_ws,
                              size_t ws_size, hipStream_t stream) {
  const float* x = (const float*)d_in[0];
  const int* mask = (const int*)d_in[1];
  const float* qkv_w = (const float*)d_in[2];
  const float* qkv_b = (const float*)d_in[3];
  const float* out_w = (const float*)d_in[4];
  const float* out_b = (const float*)d_in[5];
  float* out = (float*)d_out;

  ushort* p = (ushort*)d_ws;
  ushort* xb = p;      p += 4194304;   // x bf16 [4096][1024]      (contiguous
  ushort* qkvwb = p;   p += 3145728;   // qkv_w bf16 [3072][1024]   cvt3 dest)
  ushort* outwb = p;   p += 1048576;   // out_w bf16 [1024][1024]
  ushort* q_ws = p;    p += 4194304;   // [32][2048][64] (pre-scaled by 1/8)
  ushort* k_ws = p;    p += 4194304;   // [32][2048][64]
  ushort* vt_ws = p;   p += 4194304;   // [32][64][2048] (transposed in GEMM)
  ushort* ao_ws = p;   p += 4194304;   // [4096][1024] bf16
  int* flags = (int*)p;                // [2][32][32]

  cvt3_f32_bf16<<<4096, 256, 0, stream>>>(x, qkv_w, out_w, xb);
  mask_flags<<<2048, 256, 0, stream>>>(mask, flags);
  gemm_bt<1><<<dim3(32, 24), 256, 0, stream>>>(xb, qkvwb, qkv_b, q_ws, k_ws,
                                               vt_ws, nullptr);
  flash_attn<<<1024, 256, 0, stream>>>(q_ws, k_ws, vt_ws, mask, flags, ao_ws);
  gemm_bt<0><<<dim3(32, 8), 256, 0, stream>>>(ao_ws, outwb, out_b, nullptr,
                                              nullptr, nullptr, out);
}